// Round 4
// baseline (179.836 us; speedup 1.0000x reference)
//
#include <hip/hip_runtime.h>
#include <math.h>

#define W 512
#define H 512
#define NUM_R 725
#define NUM_T 180
#define RCHUNK 64   // rows per block; grid (180, 512/64) = 1440 blocks

// ---------------------------------------------------------------------------
// Scatter Hough. For pixel (i,j) (flat = i*512 + j) and theta t:
//   x-sweep (|s|>=|c|): sampled by r iff round((rho_r - i*c)/s) == j
//   y-sweep (|c|> |s|): sampled by r iff round((rho_r - j*s)/c) == i
// Both reduce to |u - r| <= hw,  u = (i*c + j*s + diag)/step,
//   hw = max(|s|,|c|)/(2*step)  (interval width < step => at most one r).
// u tracked in Q32 fixed point, incremented by c/step per row (refreshed from
// f64 once per 64-row block => drift <= 32 LSB ~ 7e-9). Hit-test: one unsigned
// range compare on the low 32 bits. Hits scatter to LDS racc[r] (ds_add_f32).
// ---------------------------------------------------------------------------
__global__ __launch_bounds__(256) void hough_scatter_k(const float* __restrict__ img,
                                                       float* __restrict__ out) {
    const int t   = blockIdx.x;            // theta 0..179
    const int n0  = blockIdx.y * RCHUNK;   // row-chunk base
    const int tid = threadIdx.x;

    __shared__ float racc[768];            // 725 rho bins (padded)

    // zero accumulators
    racc[tid] = 0.f;
    racc[tid + 256] = 0.f;
    racc[tid + 512] = 0.f;
    __syncthreads();

    // ---- per-theta constants (f64, same trig path validated R1-R3) ----
    const double theta = (double)t * (M_PI / 180.0);
    const double s = sin(theta);
    const double c = cos(theta);
    const double diag = sqrt(524288.0);          // sqrt(W*W + H*H)
    const double step = (2.0 * diag) / 724.0;    // np.linspace step
    const double inv_step = 1.0 / step;

    const double cstep = c * inv_step;           // du per row
    const double sstep = s * inv_step;           // du per col
    const double dstep = diag * inv_step;

    const double SC = 4294967296.0;              // 2^32
    const long long cq = (long long)rint(cstep * SC);
    const double hw = fmax(fabs(s), fabs(c)) * 0.5 * inv_step;  // in [0.176, 0.25]
    const unsigned hwq = (unsigned)(hw * SC);
    const unsigned A = 0x80000000u - hwq;        // hit iff lo32 - A <= B
    const unsigned B = 2u * hwq;

    // ---- this thread's two columns ----
    const int j0 = 2 * tid;
    const double colpart1 = (double)j0 * sstep + dstep;
    const double colpart2 = colpart1 + sstep;

    // Q32 state for row n0 (bias +2^31 so hi32 = round(u), lo32 = frac+0.5)
    const double nn = (double)n0;
    long long u1 = (long long)rint((nn * cstep + colpart1) * SC) + (1ll << 31);
    long long u2 = (long long)rint((nn * cstep + colpart2) * SC) + (1ll << 31);

    const float2* rowp = (const float2*)(img + (size_t)n0 * W) + tid;

#pragma unroll 8
    for (int j = 0; j < RCHUNK; ++j) {
        const float2 v = rowp[j * (W / 2)];
        const unsigned F1 = (unsigned)u1;
        const unsigned F2 = (unsigned)u2;
        const int r1 = (int)(u1 >> 32);
        const int r2 = (int)(u2 >> 32);
        u1 += cq;
        u2 += cq;
        if (F1 - A <= B) atomicAdd(&racc[r1], v.x);
        if (F2 - A <= B) atomicAdd(&racc[r2], v.y);
    }

    __syncthreads();

    // ---- flush partial accumulators to global (out pre-zeroed) ----
#pragma unroll
    for (int k = 0; k < 3; ++k) {
        const int r = tid + 256 * k;
        if (r < NUM_R) atomicAdd(&out[(size_t)r * NUM_T + t], racc[r]);
    }
}

extern "C" void kernel_launch(void* const* d_in, const int* in_sizes, int n_in,
                              void* d_out, int out_size, void* d_ws, size_t ws_size,
                              hipStream_t stream) {
    const float* img = (const float*)d_in[0];
    float* out = (float*)d_out;

    // out is poisoned before every timed call; zero it (atomic accumulation).
    hipMemsetAsync(d_out, 0, (size_t)NUM_R * NUM_T * sizeof(float), stream);

    hough_scatter_k<<<dim3(NUM_T, H / RCHUNK), dim3(256), 0, stream>>>(img, out);
}